// Round 10
// baseline (65.943 us; speedup 1.0000x reference)
//
#include <hip/hip_runtime.h>

#define DD 2048
#define BB 16

typedef float f32x4 __attribute__((ext_vector_type(4)));
typedef short bf16x8 __attribute__((ext_vector_type(8)));

static __device__ inline short bfbits(float f) {
    __bf16 h = (__bf16)f;                      // compiles to v_cvt_pk_bf16_f32 pairs
    return __builtin_bit_cast(short, h);
}

static __device__ inline bf16x8 cvt8(f32x4 a, f32x4 b) {
    bf16x8 r;
#pragma unroll
    for (int e = 0; e < 4; ++e) {
        r[e]     = bfbits(a[e]);
        r[4 + e] = bfbits(b[e]);
    }
    return r;
}

static __device__ inline float sigmoidf_(float s) { return 1.f / (1.f + expf(-s)); }

// ---------------------------------------------------------------------------
// gemm (unchanged from R9): raw[gate][b][j] = bias[j] + sum_k W[j,k]*xt[b,k].
// Block = (j-tile of 16, gate); 8 waves = 8 K-ranges of 256 (8 MFMAs each).
// C/D layout (m89-verified): col = lane&15 (b), row = (lane>>4)*4 + reg.
// ---------------------------------------------------------------------------
__global__ __launch_bounds__(512) void gemm_kernel(
    const float* __restrict__ xt,
    const float* __restrict__ Wa, const float* __restrict__ Wx,
    const float* __restrict__ ba, const float* __restrict__ bx,
    float* __restrict__ rawA, float* __restrict__ rawX)
{
    const int gate = blockIdx.x & 1;
    const int jt   = blockIdx.x >> 1;
    const int wv   = threadIdx.x >> 6;    // 0..7 : K-range
    const int lane = threadIdx.x & 63;
    const int mn   = lane & 15;
    const int kc   = lane >> 4;           // 0..3

    const float* W = gate ? Wx : Wa;
    const float* wrow = W  + (size_t)(jt * 16 + mn) * DD;
    const float* xrow = xt + (size_t)mn * DD;
    const int kbase = wv * 256 + kc * 8;

    f32x4 acc = {0.f, 0.f, 0.f, 0.f};
#pragma unroll
    for (int s = 0; s < 8; ++s) {
        const int k = kbase + s * 32;
        const f32x4 wa0 = *(const f32x4*)(wrow + k);
        const f32x4 wa1 = *(const f32x4*)(wrow + k + 4);
        const f32x4 xb0 = *(const f32x4*)(xrow + k);
        const f32x4 xb1 = *(const f32x4*)(xrow + k + 4);
        const bf16x8 af  = cvt8(wa0, wa1);
        const bf16x8 bf_ = cvt8(xb0, xb1);
        acc = __builtin_amdgcn_mfma_f32_16x16x32_bf16(af, bf_, acc, 0, 0, 0);
    }

    __shared__ float part[8][256];
#pragma unroll
    for (int r = 0; r < 4; ++r) part[wv][lane * 4 + r] = acc[r];
    __syncthreads();

    if (threadIdx.x < 256) {
        const int t = threadIdx.x;
        float s = 0.f;
#pragma unroll
        for (int w = 0; w < 8; ++w) s += part[w][t];
        const int l   = t >> 2;
        const int r   = t & 3;
        const int row = ((l >> 4) << 2) + r;   // j within tile
        const int col = l & 15;                // b
        const int j   = jt * 16 + row;
        s += (gate ? bx : ba)[j];
        (gate ? rawX : rawA)[col * DD + j] = s;
    }
}

// ---------------------------------------------------------------------------
// fill v5: R6 topology (4096 blocks x 8 rows, 16 blocks/CU) + fused finalize
// prologue. Each thread computes u/dv for ITS OWN 8 j-columns from the raw
// sums (redundant across row-groups, hidden under the store stream), then
// streams the same 16 coalesced float4 stores as R6.
// ---------------------------------------------------------------------------
__global__ __launch_bounds__(256) void fill_kernel(
    const float* __restrict__ xt, const float* __restrict__ h,
    const float* __restrict__ rawA, const float* __restrict__ rawX,
    const float* __restrict__ Lam,
    float4* __restrict__ out)
{
    const int blk = blockIdx.x;       // 0..4095
    const int b   = blk >> 8;         // 0..15
    const int ig  = blk & 255;        // 0..255
    const int i0  = ig << 3;          // 8 rows starting here
    const int t   = threadIdx.x;

    float4 u[2], dvv[2];
#pragma unroll
    for (int hh = 0; hh < 2; ++hh) {
        const int j0 = hh * 1024 + t * 4;
        const f32x4 sa  = *(const f32x4*)(rawA + b * DD + j0);
        const f32x4 sx  = *(const f32x4*)(rawX + b * DD + j0);
        const f32x4 xv  = *(const f32x4*)(xt   + b * DD + j0);
        const f32x4 hv  = *(const f32x4*)(h    + b * DD + j0);
        const f32x4 lam = *(const f32x4*)(Lam + j0);
#pragma unroll
        for (int e = 0; e < 4; ++e) {
            const float rt  = sigmoidf_(sa[e]);
            const float itg = sigmoidf_(sx[e]);
            const float log_a = -log1pf(expf(-lam[e]));   // -softplus(-Lam)
            const float a = expf(log_a * rt * 0.125f);    // / C, C = 8
            const float uu = sqrtf(fmaxf(0.f, 1.f - a * a)) * (itg * xv[e]);
            ((float*)&u[hh])[e]   = uu;
            ((float*)&dvv[hh])[e] = fmaf(a, hv[e], uu);
        }
    }

    float4* orow = out + ((size_t)b << 20) + ((size_t)i0 << 9);
#pragma unroll
    for (int r = 0; r < 8; ++r) {
        const int i   = i0 + r;
        const int dj4 = i >> 2;
        float4 w0 = u[0], w1 = u[1];
        if (dj4 == t) {
            ((float*)&w0)[i & 3] = ((const float*)&dvv[0])[i & 3];
        } else if (dj4 == 256 + t) {
            ((float*)&w1)[i & 3] = ((const float*)&dvv[1])[i & 3];
        }
        orow[t]       = w0;
        orow[256 + t] = w1;
        orow += DD / 4;
    }
}

extern "C" void kernel_launch(void* const* d_in, const int* in_sizes, int n_in,
                              void* d_out, int out_size, void* d_ws, size_t ws_size,
                              hipStream_t stream) {
    const float* xt  = (const float*)d_in[0];
    const float* h   = (const float*)d_in[1];
    const float* Wa  = (const float*)d_in[2];
    const float* Wx  = (const float*)d_in[3];
    const float* ba  = (const float*)d_in[4];
    const float* bx  = (const float*)d_in[5];
    const float* Lam = (const float*)d_in[6];

    float* rawA = (float*)d_ws;          // [B, D]  biased A sums
    float* rawX = rawA + BB * DD;        // [B, D]  biased X sums

    gemm_kernel<<<256, 512, 0, stream>>>(xt, Wa, Wx, ba, bx, rawA, rawX);
    fill_kernel<<<BB * (DD / 8), 256, 0, stream>>>(xt, h, rawA, rawX, Lam, (float4*)d_out);
}

// Round 11
// 60.216 us; speedup vs baseline: 1.0951x; 1.0951x over previous
//
#include <hip/hip_runtime.h>

#define DD 2048
#define BB 16

typedef float f32x4 __attribute__((ext_vector_type(4)));
typedef short bf16x8 __attribute__((ext_vector_type(8)));

static __device__ inline short bfbits(float f) {
    __bf16 h = (__bf16)f;                      // compiles to v_cvt_pk_bf16_f32 pairs
    return __builtin_bit_cast(short, h);
}

static __device__ inline bf16x8 cvt8(f32x4 a, f32x4 b) {
    bf16x8 r;
#pragma unroll
    for (int e = 0; e < 4; ++e) {
        r[e]     = bfbits(a[e]);
        r[4 + e] = bfbits(b[e]);
    }
    return r;
}

// ---------------------------------------------------------------------------
// gemm v2 (finalize fused at 1x redundancy): block = 8 output columns.
// A-frag rows 0-7 = Wa[j0..j0+7], rows 8-15 = Wx[j0..j0+7]; B = xt.
// One MFMA chain computes BOTH gates (C row m depends only on A row m).
// 8 waves split K into 256-ranges; LDS combine; 128 epilogue threads each
// own one (b,j) with both gate sums -> full finalize inline -> u, dv.
// C/D layout (m89-verified): col = lane&15 (b), row = (lane>>4)*4 + reg.
// ---------------------------------------------------------------------------
__global__ __launch_bounds__(512) void gemm_kernel(
    const float* __restrict__ xt, const float* __restrict__ h,
    const float* __restrict__ Wa, const float* __restrict__ Wx,
    const float* __restrict__ ba, const float* __restrict__ bx,
    const float* __restrict__ Lam,
    float* __restrict__ u_ws, float* __restrict__ dv_ws)
{
    const int j0   = blockIdx.x * 8;      // 256 blocks
    const int wv   = threadIdx.x >> 6;    // 0..7 : K-range
    const int lane = threadIdx.x & 63;
    const int mn   = lane & 15;
    const int kc   = lane >> 4;           // 0..3

    // rows 0-7: Wa; rows 8-15: Wx (same j-range)
    const float* wrow = (mn < 8) ? (Wa + (size_t)(j0 + mn) * DD)
                                 : (Wx + (size_t)(j0 + (mn & 7)) * DD);
    const float* xrow = xt + (size_t)mn * DD;
    const int kbase = wv * 256 + kc * 8;

    f32x4 acc = {0.f, 0.f, 0.f, 0.f};
#pragma unroll
    for (int s = 0; s < 8; ++s) {
        const int k = kbase + s * 32;
        const f32x4 wa0 = *(const f32x4*)(wrow + k);
        const f32x4 wa1 = *(const f32x4*)(wrow + k + 4);
        const f32x4 xb0 = *(const f32x4*)(xrow + k);
        const f32x4 xb1 = *(const f32x4*)(xrow + k + 4);
        acc = __builtin_amdgcn_mfma_f32_16x16x32_bf16(cvt8(wa0, wa1), cvt8(xb0, xb1), acc, 0, 0, 0);
    }

    __shared__ float part[8][256];
#pragma unroll
    for (int r = 0; r < 4; ++r) part[wv][lane * 4 + r] = acc[r];
    __syncthreads();

    __shared__ float comb[16][17];        // [row][b], padded
    if (threadIdx.x < 256) {
        const int t = threadIdx.x;
        float s = 0.f;
#pragma unroll
        for (int w = 0; w < 8; ++w) s += part[w][t];
        const int l   = t >> 2;
        const int r   = t & 3;
        const int row = ((l >> 4) << 2) + r;   // 0..15: 0-7 A-gate, 8-15 X-gate
        const int col = l & 15;                // b
        comb[row][col] = s;
    }
    __syncthreads();

    if (threadIdx.x < 128) {
        const int b  = threadIdx.x >> 3;       // 0..15
        const int jr = threadIdx.x & 7;        // 0..7  (contiguous j per 8 threads)
        const int j  = j0 + jr;
        const float sA = comb[jr][b]     + ba[j];
        const float sX = comb[jr + 8][b] + bx[j];
        const float rt  = 1.f / (1.f + expf(-sA));
        const float itg = 1.f / (1.f + expf(-sX));
        const float log_a = -log1pf(expf(-Lam[j]));    // -softplus(-Lam)
        const float a = expf(log_a * rt * 0.125f);     // / C, C = 8
        const float u = sqrtf(fmaxf(0.f, 1.f - a * a)) * (itg * xt[b * DD + j]);
        const float dv = fmaf(a, h[b * DD + j], u);
        u_ws[b * DD + j]  = u;
        dv_ws[b * DD + j] = dv;
    }
}

// ---------------------------------------------------------------------------
// fill (unchanged — R6/R9 best measured): block = (b, 8 rows); u cached in
// regs, 16 coalesced float4 stores/thread, diagonal patched inline.
// ---------------------------------------------------------------------------
__global__ __launch_bounds__(256) void fill_kernel(
    const float4* __restrict__ u4, const float* __restrict__ dv,
    float4* __restrict__ out)
{
    const int blk = blockIdx.x;       // 0..4095
    const int b   = blk >> 8;         // 0..15
    const int ig  = blk & 255;        // 0..255
    const int i0  = ig << 3;          // 8 rows starting here
    const int t   = threadIdx.x;

    const float4 v0 = u4[(b << 9) + t];         // j4 = t
    const float4 v1 = u4[(b << 9) + 256 + t];   // j4 = 256 + t

    float4* orow = out + ((size_t)b << 20) + ((size_t)i0 << 9);
#pragma unroll
    for (int r = 0; r < 8; ++r) {
        const int i   = i0 + r;
        const int dj4 = i >> 2;
        float4 w0 = v0, w1 = v1;
        if (dj4 == t) {
            ((float*)&w0)[i & 3] = dv[(b << 11) + i];
        } else if (dj4 == 256 + t) {
            ((float*)&w1)[i & 3] = dv[(b << 11) + i];
        }
        orow[t]       = w0;
        orow[256 + t] = w1;
        orow += DD / 4;
    }
}

extern "C" void kernel_launch(void* const* d_in, const int* in_sizes, int n_in,
                              void* d_out, int out_size, void* d_ws, size_t ws_size,
                              hipStream_t stream) {
    const float* xt  = (const float*)d_in[0];
    const float* h   = (const float*)d_in[1];
    const float* Wa  = (const float*)d_in[2];
    const float* Wx  = (const float*)d_in[3];
    const float* ba  = (const float*)d_in[4];
    const float* bx  = (const float*)d_in[5];
    const float* Lam = (const float*)d_in[6];

    float* u_ws  = (float*)d_ws;          // [B, D]
    float* dv_ws = u_ws + BB * DD;        // [B, D]

    gemm_kernel<<<DD / 8, 512, 0, stream>>>(xt, h, Wa, Wx, ba, bx, Lam, u_ws, dv_ws);
    fill_kernel<<<BB * (DD / 8), 256, 0, stream>>>((const float4*)u_ws, dv_ws, (float4*)d_out);
}